// Round 8
// baseline (120.653 us; speedup 1.0000x reference)
//
#include <hip/hip_runtime.h>
#include <cmath>

#define BN 32
#define AN 32768
#define GN 64
#define APT 2                      // anchors per thread in k_fused
#define TPB 256                    // threads per block in k_fused
#define ANCH_PER_BLK (APT * TPB)   // 512
#define CAP 8192                   // LDS survivor capacity in k_neg

// ---------------- workspace layout (bytes) ----------------
// 0     : int   totN        (total num_pos, atomic)
// 4     : float totL        (total loc sum, atomic)
// 8     : float totPC       (total pos+neg conf sum, atomic)
// 12    : uint  done        (finished-block counter)
// 1024  : u64   gkey[B*G]   (16 KB, atomicMax)
// 17408 : u8    abyte[B*A]  (1 MB, fully overwritten by k_fused)
#define WS_TOTN(ws)   ((int*)(ws))
#define WS_TOTL(ws)   ((float*)((char*)(ws) + 4))
#define WS_TOTPC(ws)  ((float*)((char*)(ws) + 8))
#define WS_DONE(ws)   ((unsigned*)((char*)(ws) + 12))
#define WS_GKEY(ws)   ((unsigned long long*)((char*)(ws) + 1024))
#define WS_ABYTE(ws)  ((unsigned char*)((char*)(ws) + 17408))
#define WS_ZERO_BYTES 17408

__device__ __forceinline__ float negloss(float p) {
    // -log(1-p), clamped like torch BCELoss; > 0 for all p in (0,1)
    return -fmaxf(log1pf(-p), -100.0f);
}

// ===================== k_init: zero scalars + gkey =====================
__global__ __launch_bounds__(1024) void k_init(unsigned* __restrict__ ws) {
    int tid = threadIdx.x;
    for (int i = tid; i < WS_ZERO_BYTES / 4; i += 1024) ws[i] = 0u;
}

// ===================== fused IoU pass (unchanged from round 7) =====================
__global__ __launch_bounds__(TPB, 8) void k_fused(const float* __restrict__ anchors,
                                                  const float* __restrict__ gt,
                                                  unsigned long long* __restrict__ gkey,
                                                  unsigned char* __restrict__ abyte) {
    __shared__ float sgt[5][GN];               // x0,y0,x1,y1,area (SoA)
    __shared__ unsigned long long skey2[GN];

    int b = blockIdx.y;
    int tid = threadIdx.x;
    int lane = tid & 63;
    int blockbase = blockIdx.x * ANCH_PER_BLK;

    if (tid < GN) {
        float4 g = ((const float4*)gt)[b * GN + tid];
        sgt[0][tid] = g.x; sgt[1][tid] = g.y;
        sgt[2][tid] = g.z; sgt[3][tid] = g.w;
        sgt[4][tid] = (g.z - g.x) * (g.w - g.y);
        skey2[tid] = 0ull;
    }
    __syncthreads();

    unsigned a0 = (unsigned)(blockbase + tid);
    unsigned a1 = a0 + TPB;
    float4 ab0 = ((const float4*)anchors)[a0];
    float4 ab1 = ((const float4*)anchors)[a1];
    float sa0 = (ab0.z - ab0.x) * (ab0.w - ab0.y) + 1e-6f;
    float sa1 = (ab1.z - ab1.x) * (ab1.w - ab1.y) + 1e-6f;

    float bv0 = -1.0f, bv1 = -1.0f;
    int bg0 = 0, bg1 = 0;

#pragma unroll 4
    for (int j = 0; j < GN; ++j) {
        int g = (lane + j) & 63;
        float gx0 = sgt[0][g], gy0 = sgt[1][g];
        float gx1 = sgt[2][g], gy1 = sgt[3][g];
        float gA  = sgt[4][g];

        float ix0 = fmaxf(ab0.x, gx0), iy0 = fmaxf(ab0.y, gy0);
        float ix1 = fminf(ab0.z, gx1), iy1 = fminf(ab0.w, gy1);
        float iw = fmaxf(ix1 - ix0, 0.0f), ih = fmaxf(iy1 - iy0, 0.0f);
        float inter0 = iw * ih;
        float v0 = inter0 * __builtin_amdgcn_rcpf((sa0 + gA) - inter0);

        ix0 = fmaxf(ab1.x, gx0); iy0 = fmaxf(ab1.y, gy0);
        ix1 = fminf(ab1.z, gx1); iy1 = fminf(ab1.w, gy1);
        iw = fmaxf(ix1 - ix0, 0.0f); ih = fmaxf(iy1 - iy0, 0.0f);
        float inter1 = iw * ih;
        float v1 = inter1 * __builtin_amdgcn_rcpf((sa1 + gA) - inter1);

        if (v0 > bv0) { bv0 = v0; bg0 = g; }
        if (v1 > bv1) { bv1 = v1; bg1 = g; }

        float vm = v0; unsigned am = a0;
        if (v1 > vm) { vm = v1; am = a1; }
        unsigned long long key = ((unsigned long long)__float_as_uint(vm) << 32)
                               | (unsigned long long)(~am);
        atomicMax(&skey2[g], key);
    }
    __syncthreads();

    size_t base = (size_t)b * AN;
    abyte[base + a0] = (unsigned char)(((bv0 > 0.5f) ? 0x80u : 0u) | (unsigned)bg0);
    abyte[base + a1] = (unsigned char)(((bv1 > 0.5f) ? 0x80u : 0u) | (unsigned)bg1);

    if (tid < GN) {
        unsigned long long kk = skey2[tid];
        atomicMax(&gkey[b * GN + tid], kk);
    }
}

// ===================== k_neg2: full per-image tail, one block per image =====================
__global__ __launch_bounds__(1024) void k_neg2(const float* __restrict__ bbox,
                                               const float* __restrict__ conf,
                                               const float* __restrict__ gt,
                                               const unsigned long long* __restrict__ gkey,
                                               const unsigned char* __restrict__ abyte,
                                               int* __restrict__ totN,
                                               float* __restrict__ totL,
                                               float* __restrict__ totPC,
                                               unsigned* __restrict__ done,
                                               float* __restrict__ out) {
    __shared__ unsigned hist[4096];
    __shared__ float sv[CAP];
    __shared__ unsigned bitmap[1024];
    __shared__ float4 sgcs[GN];
    __shared__ float redA[16];
    __shared__ int   redN[16];
    __shared__ int   s_np;
    __shared__ float s_loc, s_pc;
    __shared__ unsigned s_cnt, s_sel, s_krem;

    int b = blockIdx.x, tid = threadIdx.x;
    int lane = tid & 63, wave = tid >> 6;

    for (int i = tid; i < 4096; i += 1024) hist[i] = 0;
    bitmap[tid] = 0;
    if (tid == 0) s_cnt = 0;
    if (tid < GN) {
        float4 g = ((const float4*)gt)[b * GN + tid];
        sgcs[tid] = make_float4((g.x + g.z) * 0.5f, (g.y + g.w) * 0.5f,
                                g.z - g.x, g.w - g.y);
    }
    __syncthreads();
    if (tid < GN) {
        unsigned long long kk = gkey[b * GN + tid];
        unsigned idx = ~(unsigned)(kk & 0xFFFFFFFFull);
        atomicOr(&bitmap[idx >> 5], 1u << (idx & 31));
    }
    __syncthreads();

    const float4* c4p = (const float4*)(conf + (size_t)b * AN);
    const uchar4* b4p = (const uchar4*)(abyte + (size_t)b * AN);
    const float4* bb4p = ((const float4*)bbox) + (size_t)b * AN;

    // ---- pass 1: scalars + histogram (forced positives exact via bitmap)
    float locv = 0.0f, pcv = 0.0f;
    int npv = 0;
#pragma unroll
    for (int it = 0; it < 8; ++it) {
        int i4 = tid + it * 1024;
        float4 c4 = c4p[i4];
        uchar4 u4 = b4p[i4];
        int li = i4 * 4;
        unsigned fb = (bitmap[li >> 5] >> (li & 31)) & 0xFu;
        float cc[4] = {c4.x, c4.y, c4.z, c4.w};
        unsigned by[4] = {u4.x, u4.y, u4.z, u4.w};
#pragma unroll
        for (int e = 0; e < 4; ++e) {
            float p = cc[e];
            bool pos = (by[e] & 0x80u) || ((fb >> e) & 1u);
            float v;
            if (pos) {
                float4 bb = bb4p[li + e];
                float4 m = sgcs[by[e] & 63u];
                float d0 = (bb.x + bb.z) * 0.5f - m.x;
                float d1 = (bb.y + bb.w) * 0.5f - m.y;
                float d2 = (bb.z - bb.x) - m.z;
                float d3 = (bb.w - bb.y) - m.w;
                float ad = fabsf(d0); float s = (ad < 1.0f) ? 0.5f * d0 * d0 : ad - 0.5f;
                ad = fabsf(d1); s += (ad < 1.0f) ? 0.5f * d1 * d1 : ad - 0.5f;
                ad = fabsf(d2); s += (ad < 1.0f) ? 0.5f * d2 * d2 : ad - 0.5f;
                ad = fabsf(d3); s += (ad < 1.0f) ? 0.5f * d3 * d3 : ad - 0.5f;
                locv += s;
                pcv += -fmaxf(logf(p), -100.0f);
                npv += 1;
                v = 0.0f;                       // bin 0, never selected (k <= #neg)
            } else {
                v = negloss(p);
            }
            atomicAdd(&hist[__float_as_uint(v) >> 20], 1u);
        }
    }
    for (int off = 32; off; off >>= 1) {
        locv += __shfl_xor(locv, off);
        pcv  += __shfl_xor(pcv, off);
        npv  += __shfl_xor(npv, off);
    }
    if (lane == 0) { redA[wave] = locv; redN[wave] = npv; }
    __syncthreads();
    if (tid == 0) {
        float L = 0.0f; int N = 0;
        for (int w = 0; w < 16; ++w) { L += redA[w]; N += redN[w]; }
        s_loc = L; s_np = N;
    }
    __syncthreads();
    if (lane == 0) redA[wave] = pcv;
    __syncthreads();
    if (tid == 0) {
        float P = 0.0f;
        for (int w = 0; w < 16; ++w) P += redA[w];
        s_pc = P;
    }
    __syncthreads();

    int np = s_np;
    unsigned k = (unsigned)min(3 * np, AN - np);
    float nc = 0.0f;

    if (k > 0) {
        // ---- select round 1 over hist[4096] (descending): two-level wave scan
        if (tid < 64) {
            unsigned c = 0;
            int base = tid * 64;
#pragma unroll
            for (int i = 0; i < 64; ++i) c += hist[base + ((tid + i) & 63)];
            unsigned S = c;
#pragma unroll
            for (int d = 1; d < 64; d <<= 1) { unsigned t = __shfl_down(S, d); if (tid + d < 64) S += t; }
            unsigned E = S - c;
            unsigned long long mk = __ballot(E < k && k <= S);
            int bl = __ffsll(mk) - 1;
            unsigned kin = k - __shfl(E, bl);
            unsigned h = hist[bl * 64 + tid];
            unsigned S2 = h;
#pragma unroll
            for (int d = 1; d < 64; d <<= 1) { unsigned t = __shfl_down(S2, d); if (tid + d < 64) S2 += t; }
            unsigned E2 = S2 - h;
            unsigned long long mk2 = __ballot(E2 < kin && kin <= S2);
            int bin_l = __ffsll(mk2) - 1;
            unsigned E2b = __shfl(E2, bin_l);
            if (tid == 0) { s_sel = (unsigned)(bl * 64 + bin_l); s_krem = kin - E2b; }
        }
        __syncthreads();
        unsigned sel1 = s_sel, krem1 = s_krem;
        __syncthreads();
        for (int i = tid; i < 4096; i += 1024) hist[i] = 0;
        __syncthreads();

        // ---- pass 2: strictly-above sum + LDS compaction (bit-identical v)
        float acc = 0.0f;
#pragma unroll
        for (int it = 0; it < 8; ++it) {
            int i4 = tid + it * 1024;
            float4 c4 = c4p[i4];
            uchar4 u4 = b4p[i4];
            int li = i4 * 4;
            unsigned fb = (bitmap[li >> 5] >> (li & 31)) & 0xFu;
            float cc[4] = {c4.x, c4.y, c4.z, c4.w};
            unsigned by[4] = {u4.x, u4.y, u4.z, u4.w};
#pragma unroll
            for (int e = 0; e < 4; ++e) {
                bool pos = (by[e] & 0x80u) || ((fb >> e) & 1u);
                float v = pos ? 0.0f : negloss(cc[e]);
                unsigned bin = __float_as_uint(v) >> 20;
                if (bin > sel1) acc += v;
                else if (bin == sel1) {
                    unsigned p = atomicAdd(&s_cnt, 1u);
                    if (p < CAP) sv[p] = v;
                }
            }
        }
        __syncthreads();
        unsigned n = min(s_cnt, (unsigned)CAP);

        // ---- round A: 12 bits (key>>8)&0xFFF over survivors
        for (unsigned i = tid; i < n; i += 1024)
            atomicAdd(&hist[(__float_as_uint(sv[i]) >> 8) & 0xFFFu], 1u);
        __syncthreads();
        if (tid < 64) {
            unsigned c = 0;
            int base = tid * 64;
#pragma unroll
            for (int i = 0; i < 64; ++i) c += hist[base + ((tid + i) & 63)];
            unsigned S = c;
#pragma unroll
            for (int d = 1; d < 64; d <<= 1) { unsigned t = __shfl_down(S, d); if (tid + d < 64) S += t; }
            unsigned E = S - c;
            unsigned long long mk = __ballot(E < krem1 && krem1 <= S);
            int bl = __ffsll(mk) - 1;
            unsigned kin = krem1 - __shfl(E, bl);
            unsigned h = hist[bl * 64 + tid];
            unsigned S2 = h;
#pragma unroll
            for (int d = 1; d < 64; d <<= 1) { unsigned t = __shfl_down(S2, d); if (tid + d < 64) S2 += t; }
            unsigned E2 = S2 - h;
            unsigned long long mk2 = __ballot(E2 < kin && kin <= S2);
            int bin_l = __ffsll(mk2) - 1;
            unsigned E2b = __shfl(E2, bin_l);
            if (tid == 0) { s_sel = (unsigned)(bl * 64 + bin_l); s_krem = kin - E2b; }
        }
        __syncthreads();
        unsigned selA = s_sel, krem2 = s_krem;
        __syncthreads();
        if (tid < 256) hist[tid] = 0;
        __syncthreads();

        // ---- round B: low 8 bits, masked to selA
        for (unsigned i = tid; i < n; i += 1024) {
            unsigned key = __float_as_uint(sv[i]);
            if (((key >> 8) & 0xFFFu) == selA) atomicAdd(&hist[key & 0xFFu], 1u);
        }
        __syncthreads();
        if (tid < 64) {
            int base = tid * 4;
            unsigned c = 0;
#pragma unroll
            for (int i = 0; i < 4; ++i) c += hist[base + i];
            unsigned S = c;
#pragma unroll
            for (int d = 1; d < 64; d <<= 1) { unsigned t = __shfl_down(S, d); if (tid + d < 64) S += t; }
            unsigned E = S - c;
            unsigned long long mk = __ballot(E < krem2 && krem2 <= S);
            int bl = __ffsll(mk) - 1;
            if (tid == bl) {
                unsigned cum = E;
                for (int bin = base + 3; bin >= base; --bin) {
                    unsigned h = hist[bin];
                    cum += h;
                    if (cum >= krem2) { s_sel = (unsigned)bin; s_krem = krem2 - (cum - h); break; }
                }
            }
        }
        __syncthreads();
        unsigned Tkey = (sel1 << 20) | (selA << 8) | s_sel;
        unsigned kremF = s_krem;
        float T = __uint_as_float(Tkey);   // exact k-th largest value

        float part = acc;
        for (unsigned i = tid; i < n; i += 1024)
            if (__float_as_uint(sv[i]) > Tkey) part += sv[i];
        for (int off = 32; off; off >>= 1) part += __shfl_xor(part, off);
        if (lane == 0) redA[wave] = part;
        __syncthreads();
        if (tid == 0) {
            float t = 0.0f;
            for (int w = 0; w < 16; ++w) t += redA[w];
            nc = t + (float)kremF * T;
        }
    }

    // ---- finalize: cross-block traffic via device-scope atomics only
    if (tid == 0) {
        atomicAdd(totN, np);
        atomicAdd(totL, s_loc);
        atomicAdd(totPC, s_pc + nc);
        __threadfence();
        unsigned old = atomicAdd(done, 1u);
        if (old == BN - 1) {            // last image finished -> final reduction
            int   N  = atomicAdd(totN, 0);
            float L  = atomicAdd(totL, 0.0f);
            float PC = atomicAdd(totPC, 0.0f);
            float tp = (float)max(1, N);
            float loc_loss = L / tp;
            float conf_loss = PC / tp;
            out[0] = loc_loss + conf_loss;
            out[1] = conf_loss;
            out[2] = loc_loss;
        }
    }
}

extern "C" void kernel_launch(void* const* d_in, const int* in_sizes, int n_in,
                              void* d_out, int out_size, void* d_ws, size_t ws_size,
                              hipStream_t stream) {
    const float* bbox    = (const float*)d_in[0];   // [B,A,4]
    const float* conf    = (const float*)d_in[1];   // [B,A]
    const float* anchors = (const float*)d_in[2];   // [A,4]
    const float* gt      = (const float*)d_in[3];   // [B,G,4]
    float* out = (float*)d_out;

    k_init<<<1, 1024, 0, stream>>>((unsigned*)d_ws);

    dim3 g1(AN / ANCH_PER_BLK, BN);   // (64, 32) -> 32 waves/CU
    k_fused<<<g1, TPB, 0, stream>>>(anchors, gt, WS_GKEY(d_ws), WS_ABYTE(d_ws));

    k_neg2<<<BN, 1024, 0, stream>>>(bbox, conf, gt, WS_GKEY(d_ws), WS_ABYTE(d_ws),
                                    WS_TOTN(d_ws), WS_TOTL(d_ws), WS_TOTPC(d_ws),
                                    WS_DONE(d_ws), out);
}

// Round 9
// 77.012 us; speedup vs baseline: 1.5667x; 1.5667x over previous
//
#include <hip/hip_runtime.h>
#include <cmath>

#define BN 32
#define AN 32768
#define GN 64
#define APT 2                      // anchors per thread in k_fused
#define TPB 256                    // threads per block in k_fused
#define ANCH_PER_BLK (APT * TPB)   // 512
#define NBLK 8                     // k_prep blocks per image
#define CAP 8192                   // LDS survivor capacity in k_neg

// ---------------- workspace layout (bytes) ----------------
// 0       : int   totN         (total num_pos, atomic)
// 4       : float totL         (total loc sum, atomic)
// 8       : float totPC        (total pos+neg conf sum, atomic)
// 12      : uint  done         (finished-image counter)
// 16      : int   num_pos[32]  (per-image, atomic)
// 1024    : u64   gkey[B*G]            (16 KB, atomicMax)
// 17408   : uint  hist1[B][NBLK][4096] (4 MB, plain stores - no zeroing)
// 4211712 : u8    abyte[B*A]           (1 MB, fully overwritten)
#define WS_TOTN(ws)    ((int*)(ws))
#define WS_TOTL(ws)    ((float*)((char*)(ws) + 4))
#define WS_TOTPC(ws)   ((float*)((char*)(ws) + 8))
#define WS_DONE(ws)    ((unsigned*)((char*)(ws) + 12))
#define WS_NUMPOS(ws)  ((int*)((char*)(ws) + 16))
#define WS_GKEY(ws)    ((unsigned long long*)((char*)(ws) + 1024))
#define WS_HIST1(ws)   ((unsigned*)((char*)(ws) + 17408))
#define WS_ABYTE(ws)   ((unsigned char*)((char*)(ws) + 4211712))
#define WS_ZERO_WORDS  (17408 / 4)      // scalars + num_pos + gkey

#define LN2F 0.69314718056f

__device__ __forceinline__ float negloss(float p) {
    // -log(1-p); p <= 1-1e-4 so log(1-p) >= -9.22 (clamp at -100 never binds,
    // kept for safety). v_log_f32 fast path; MUST be identical in k_prep & k_neg.
    return -fmaxf(__log2f(1.0f - p) * LN2F, -100.0f);
}
__device__ __forceinline__ float posbce(float p) {
    // -log(p); p >= 1e-4 so >= -9.22; clamp kept for safety.
    return -fmaxf(__log2f(p) * LN2F, -100.0f);
}

// ===================== k_init: zero scalars + num_pos + gkey =====================
__global__ __launch_bounds__(256) void k_init(unsigned* __restrict__ ws) {
    int i = blockIdx.x * 256 + threadIdx.x;
    for (; i < WS_ZERO_WORDS; i += 32 * 256) ws[i] = 0u;
}

// ===================== fused IoU pass (unchanged, proven r7/r8) =====================
__global__ __launch_bounds__(TPB, 8) void k_fused(const float* __restrict__ anchors,
                                                  const float* __restrict__ gt,
                                                  unsigned long long* __restrict__ gkey,
                                                  unsigned char* __restrict__ abyte) {
    __shared__ float sgt[5][GN];               // x0,y0,x1,y1,area (SoA)
    __shared__ unsigned long long skey2[GN];

    int b = blockIdx.y;
    int tid = threadIdx.x;
    int lane = tid & 63;
    int blockbase = blockIdx.x * ANCH_PER_BLK;

    if (tid < GN) {
        float4 g = ((const float4*)gt)[b * GN + tid];
        sgt[0][tid] = g.x; sgt[1][tid] = g.y;
        sgt[2][tid] = g.z; sgt[3][tid] = g.w;
        sgt[4][tid] = (g.z - g.x) * (g.w - g.y);
        skey2[tid] = 0ull;
    }
    __syncthreads();

    unsigned a0 = (unsigned)(blockbase + tid);
    unsigned a1 = a0 + TPB;
    float4 ab0 = ((const float4*)anchors)[a0];
    float4 ab1 = ((const float4*)anchors)[a1];
    float sa0 = (ab0.z - ab0.x) * (ab0.w - ab0.y) + 1e-6f;
    float sa1 = (ab1.z - ab1.x) * (ab1.w - ab1.y) + 1e-6f;

    float bv0 = -1.0f, bv1 = -1.0f;
    int bg0 = 0, bg1 = 0;

#pragma unroll 4
    for (int j = 0; j < GN; ++j) {
        int g = (lane + j) & 63;
        float gx0 = sgt[0][g], gy0 = sgt[1][g];
        float gx1 = sgt[2][g], gy1 = sgt[3][g];
        float gA  = sgt[4][g];

        float ix0 = fmaxf(ab0.x, gx0), iy0 = fmaxf(ab0.y, gy0);
        float ix1 = fminf(ab0.z, gx1), iy1 = fminf(ab0.w, gy1);
        float iw = fmaxf(ix1 - ix0, 0.0f), ih = fmaxf(iy1 - iy0, 0.0f);
        float inter0 = iw * ih;
        float v0 = inter0 * __builtin_amdgcn_rcpf((sa0 + gA) - inter0);

        ix0 = fmaxf(ab1.x, gx0); iy0 = fmaxf(ab1.y, gy0);
        ix1 = fminf(ab1.z, gx1); iy1 = fminf(ab1.w, gy1);
        iw = fmaxf(ix1 - ix0, 0.0f); ih = fmaxf(iy1 - iy0, 0.0f);
        float inter1 = iw * ih;
        float v1 = inter1 * __builtin_amdgcn_rcpf((sa1 + gA) - inter1);

        if (v0 > bv0) { bv0 = v0; bg0 = g; }
        if (v1 > bv1) { bv1 = v1; bg1 = g; }

        float vm = v0; unsigned am = a0;
        if (v1 > vm) { vm = v1; am = a1; }
        unsigned long long key = ((unsigned long long)__float_as_uint(vm) << 32)
                               | (unsigned long long)(~am);
        atomicMax(&skey2[g], key);     // ds_max_u64, no return -> no dep chain
    }
    __syncthreads();

    size_t base = (size_t)b * AN;
    abyte[base + a0] = (unsigned char)(((bv0 > 0.5f) ? 0x80u : 0u) | (unsigned)bg0);
    abyte[base + a1] = (unsigned char)(((bv1 > 0.5f) ? 0x80u : 0u) | (unsigned)bg1);

    if (tid < GN) {
        unsigned long long kk = skey2[tid];
        atomicMax(&gkey[b * GN + tid], kk);
    }
}

// ===================== k_prep =====================
// grid (NBLK, 32), 1024 thr. Each block owns 4096 anchors of one image.
// pos mask, num_pos[b]/totL/totPC partials, round-1 (top-12-bit) histogram of
// neg-loss -> PLAIN stores into its own hist1 slice (no atomics, no memset).
__global__ __launch_bounds__(1024) void k_prep(const float* __restrict__ bbox,
                                               const float* __restrict__ conf,
                                               const float* __restrict__ gt,
                                               const unsigned long long* __restrict__ gkey,
                                               const unsigned char* __restrict__ abyte,
                                               unsigned* __restrict__ hist1,
                                               int* __restrict__ num_pos,
                                               float* __restrict__ totL,
                                               float* __restrict__ totPC) {
    __shared__ unsigned hist[4096];      // 16 KB
    __shared__ unsigned bitmap[128];     // forced anchors within this 4096 range
    __shared__ float4 sgcs[GN];
    __shared__ float redL[16], redP[16];
    __shared__ int   redN[16];

    int blk = blockIdx.x, b = blockIdx.y, tid = threadIdx.x;
    int abase = blk * 4096;

    for (int i = tid; i < 4096; i += 1024) hist[i] = 0;
    if (tid < 128) bitmap[tid] = 0;
    if (tid < GN) {
        float4 g = ((const float4*)gt)[b * GN + tid];
        sgcs[tid] = make_float4((g.x + g.z) * 0.5f, (g.y + g.w) * 0.5f,
                                g.z - g.x, g.w - g.y);
    }
    __syncthreads();
    if (tid < GN) {
        unsigned long long kk = gkey[b * GN + tid];
        unsigned idx = ~(unsigned)(kk & 0xFFFFFFFFull);
        if ((int)(idx >> 12) == blk)
            atomicOr(&bitmap[(idx & 4095u) >> 5], 1u << (idx & 31u));
    }
    __syncthreads();

    int li = tid * 4;                       // 4 consecutive anchors
    size_t ia = (size_t)b * AN + abase + li;
    float4 c4 = ((const float4*)conf)[ia >> 2];
    uchar4 by4 = ((const uchar4*)abyte)[ia >> 2];
    float cc[4] = {c4.x, c4.y, c4.z, c4.w};
    unsigned bys[4] = {by4.x, by4.y, by4.z, by4.w};
    unsigned fbits = (bitmap[li >> 5] >> (li & 31)) & 0xFu;

    float locv = 0.0f, pcv = 0.0f;
    int npv = 0;
#pragma unroll
    for (int e = 0; e < 4; ++e) {
        float p = cc[e];
        bool pos = (bys[e] & 0x80u) || ((fbits >> e) & 1u);
        float v;
        if (pos) {
            float4 bb = ((const float4*)bbox)[ia + e];
            float4 m = sgcs[bys[e] & 63u];
            float d0 = (bb.x + bb.z) * 0.5f - m.x;
            float d1 = (bb.y + bb.w) * 0.5f - m.y;
            float d2 = (bb.z - bb.x) - m.z;
            float d3 = (bb.w - bb.y) - m.w;
            float ad = fabsf(d0); float s = (ad < 1.0f) ? 0.5f * d0 * d0 : ad - 0.5f;
            ad = fabsf(d1); s += (ad < 1.0f) ? 0.5f * d1 * d1 : ad - 0.5f;
            ad = fabsf(d2); s += (ad < 1.0f) ? 0.5f * d2 * d2 : ad - 0.5f;
            ad = fabsf(d3); s += (ad < 1.0f) ? 0.5f * d3 * d3 : ad - 0.5f;
            locv += s;
            pcv += posbce(p);
            npv += 1;
            v = 0.0f;                       // bin 0, never selected (k <= #neg)
        } else {
            v = negloss(p);
        }
        atomicAdd(&hist[__float_as_uint(v) >> 20], 1u);
    }

    for (int off = 32; off; off >>= 1) {
        locv += __shfl_xor(locv, off);
        pcv  += __shfl_xor(pcv, off);
        npv  += __shfl_xor(npv, off);
    }
    int wave = tid >> 6, lane = tid & 63;
    if (lane == 0) { redL[wave] = locv; redP[wave] = pcv; redN[wave] = npv; }
    __syncthreads();
    if (tid == 0) {
        float L = 0.0f, P = 0.0f; int N = 0;
        for (int w = 0; w < 16; ++w) { L += redL[w]; P += redP[w]; N += redN[w]; }
        if (N) atomicAdd(&num_pos[b], N);
        atomicAdd(totL, L);
        atomicAdd(totPC, P);
    }
    __syncthreads();
    unsigned* hslice = hist1 + (size_t)(b * NBLK + blk) * 4096;
    for (int i = tid; i < 4096; i += 1024) hslice[i] = hist[i];
}

// ===================== k_neg =====================
// One block per image: sum NBLK hist slices, wave-parallel 2-level select of
// round-1 bin, ONE streaming pass over conf (identical negloss -> bit-identical
// bins), strictly-above sum + LDS compaction, two tiny radix rounds, then
// device-scope finalize (last image writes out[]).
__global__ __launch_bounds__(1024) void k_neg(const float* __restrict__ conf,
                                              const unsigned char* __restrict__ abyte,
                                              const unsigned long long* __restrict__ gkey,
                                              const unsigned* __restrict__ hist1,
                                              const int* __restrict__ num_pos,
                                              int* __restrict__ totN,
                                              float* __restrict__ totL,
                                              float* __restrict__ totPC,
                                              unsigned* __restrict__ done,
                                              float* __restrict__ out) {
    __shared__ unsigned hist[4096];     // 16 KB
    __shared__ float sv[CAP];           // 32 KB
    __shared__ unsigned bitmap[1024];   // 4 KB
    __shared__ float redL[16];
    __shared__ unsigned s_cnt, s_sel, s_krem;

    int b = blockIdx.x, tid = threadIdx.x;
    int lane = tid & 63, wave = tid >> 6;

    for (int i = tid; i < 4096; i += 1024) {
        unsigned s = 0;
#pragma unroll
        for (int t = 0; t < NBLK; ++t)
            s += hist1[(size_t)(b * NBLK + t) * 4096 + i];
        hist[i] = s;
    }
    bitmap[tid] = 0;
    if (tid == 0) s_cnt = 0;
    __syncthreads();
    if (tid < GN) {
        unsigned long long kk = gkey[b * GN + tid];
        unsigned idx = ~(unsigned)(kk & 0xFFFFFFFFull);
        atomicOr(&bitmap[idx >> 5], 1u << (idx & 31));
    }
    __syncthreads();

    int np = num_pos[b];
    unsigned k = (unsigned)min(3 * np, AN - np);
    float nc = 0.0f;

    if (k > 0) {
        // ---- select round 1 over hist[4096] (descending): two-level wave scan
        if (tid < 64) {
            unsigned c = 0;
            int base = tid * 64;
#pragma unroll
            for (int i = 0; i < 64; ++i) c += hist[base + ((tid + i) & 63)];  // rotated
            unsigned S = c;
#pragma unroll
            for (int d = 1; d < 64; d <<= 1) { unsigned t = __shfl_down(S, d); if (tid + d < 64) S += t; }
            unsigned E = S - c;
            unsigned long long mk = __ballot(E < k && k <= S);
            int bl = __ffsll(mk) - 1;
            unsigned kin = k - __shfl(E, bl);
            unsigned h = hist[bl * 64 + tid];
            unsigned S2 = h;
#pragma unroll
            for (int d = 1; d < 64; d <<= 1) { unsigned t = __shfl_down(S2, d); if (tid + d < 64) S2 += t; }
            unsigned E2 = S2 - h;
            unsigned long long mk2 = __ballot(E2 < kin && kin <= S2);
            int bin_l = __ffsll(mk2) - 1;
            unsigned E2b = __shfl(E2, bin_l);
            if (tid == 0) { s_sel = (unsigned)(bl * 64 + bin_l); s_krem = kin - E2b; }
        }
        __syncthreads();
        unsigned sel1 = s_sel, krem1 = s_krem;
        __syncthreads();
        for (int i = tid; i < 4096; i += 1024) hist[i] = 0;
        __syncthreads();

        // ---- ONE streaming pass: strictly-above sum + LDS compaction
        float acc = 0.0f;
        const float4* c4p = (const float4*)(conf + (size_t)b * AN);
        const uchar4* b4p = (const uchar4*)(abyte + (size_t)b * AN);
#pragma unroll
        for (int it = 0; it < 8; ++it) {
            int i4 = tid + it * 1024;
            float4 c4 = c4p[i4];
            uchar4 u4 = b4p[i4];
            int li = i4 * 4;
            unsigned fb = (bitmap[li >> 5] >> (li & 31)) & 0xFu;
            float cc[4] = {c4.x, c4.y, c4.z, c4.w};
            unsigned by[4] = {u4.x, u4.y, u4.z, u4.w};
#pragma unroll
            for (int e = 0; e < 4; ++e) {
                bool pos = (by[e] & 0x80u) || ((fb >> e) & 1u);
                float v = pos ? 0.0f : negloss(cc[e]);
                unsigned bin = __float_as_uint(v) >> 20;
                if (bin > sel1) acc += v;
                else if (bin == sel1) {
                    unsigned p = atomicAdd(&s_cnt, 1u);     // LDS atomic, ~1K total
                    if (p < CAP) sv[p] = v;
                }
            }
        }
        __syncthreads();
        unsigned n = min(s_cnt, (unsigned)CAP);

        // ---- round A: 12 bits (key>>8)&0xFFF over survivors
        for (unsigned i = tid; i < n; i += 1024)
            atomicAdd(&hist[(__float_as_uint(sv[i]) >> 8) & 0xFFFu], 1u);
        __syncthreads();
        if (tid < 64) {
            unsigned c = 0;
            int base = tid * 64;
#pragma unroll
            for (int i = 0; i < 64; ++i) c += hist[base + ((tid + i) & 63)];
            unsigned S = c;
#pragma unroll
            for (int d = 1; d < 64; d <<= 1) { unsigned t = __shfl_down(S, d); if (tid + d < 64) S += t; }
            unsigned E = S - c;
            unsigned long long mk = __ballot(E < krem1 && krem1 <= S);
            int bl = __ffsll(mk) - 1;
            unsigned kin = krem1 - __shfl(E, bl);
            unsigned h = hist[bl * 64 + tid];
            unsigned S2 = h;
#pragma unroll
            for (int d = 1; d < 64; d <<= 1) { unsigned t = __shfl_down(S2, d); if (tid + d < 64) S2 += t; }
            unsigned E2 = S2 - h;
            unsigned long long mk2 = __ballot(E2 < kin && kin <= S2);
            int bin_l = __ffsll(mk2) - 1;
            unsigned E2b = __shfl(E2, bin_l);
            if (tid == 0) { s_sel = (unsigned)(bl * 64 + bin_l); s_krem = kin - E2b; }
        }
        __syncthreads();
        unsigned selA = s_sel, krem2 = s_krem;
        __syncthreads();
        if (tid < 256) hist[tid] = 0;
        __syncthreads();

        // ---- round B: low 8 bits, masked to selA
        for (unsigned i = tid; i < n; i += 1024) {
            unsigned key = __float_as_uint(sv[i]);
            if (((key >> 8) & 0xFFFu) == selA) atomicAdd(&hist[key & 0xFFu], 1u);
        }
        __syncthreads();
        if (tid < 64) {
            int base = tid * 4;
            unsigned c = 0;
#pragma unroll
            for (int i = 0; i < 4; ++i) c += hist[base + i];
            unsigned S = c;
#pragma unroll
            for (int d = 1; d < 64; d <<= 1) { unsigned t = __shfl_down(S, d); if (tid + d < 64) S += t; }
            unsigned E = S - c;
            unsigned long long mk = __ballot(E < krem2 && krem2 <= S);
            int bl = __ffsll(mk) - 1;
            if (tid == bl) {
                unsigned cum = E;
                for (int bin = base + 3; bin >= base; --bin) {
                    unsigned h = hist[bin];
                    cum += h;
                    if (cum >= krem2) { s_sel = (unsigned)bin; s_krem = krem2 - (cum - h); break; }
                }
            }
        }
        __syncthreads();
        unsigned Tkey = (sel1 << 20) | (selA << 8) | s_sel;
        unsigned kremF = s_krem;
        float T = __uint_as_float(Tkey);   // exact k-th largest value

        float part = acc;
        for (unsigned i = tid; i < n; i += 1024)
            if (__float_as_uint(sv[i]) > Tkey) part += sv[i];
        for (int off = 32; off; off >>= 1) part += __shfl_xor(part, off);
        if (lane == 0) redL[wave] = part;
        __syncthreads();
        if (tid == 0) {
            float t = 0.0f;
            for (int w = 0; w < 16; ++w) t += redL[w];
            nc = t + (float)kremF * T;
        }
    }

    // ---- finalize: cross-block traffic via device-scope atomics only
    if (tid == 0) {
        atomicAdd(totN, np);
        atomicAdd(totPC, nc);
        __threadfence();
        unsigned old = atomicAdd(done, 1u);
        if (old == BN - 1) {            // last image -> final reduction
            int   N  = atomicAdd(totN, 0);
            float L  = atomicAdd(totL, 0.0f);
            float PC = atomicAdd(totPC, 0.0f);
            float tp = (float)max(1, N);
            float loc_loss = L / tp;
            float conf_loss = PC / tp;
            out[0] = loc_loss + conf_loss;
            out[1] = conf_loss;
            out[2] = loc_loss;
        }
    }
}

extern "C" void kernel_launch(void* const* d_in, const int* in_sizes, int n_in,
                              void* d_out, int out_size, void* d_ws, size_t ws_size,
                              hipStream_t stream) {
    const float* bbox    = (const float*)d_in[0];   // [B,A,4]
    const float* conf    = (const float*)d_in[1];   // [B,A]
    const float* anchors = (const float*)d_in[2];   // [A,4]
    const float* gt      = (const float*)d_in[3];   // [B,G,4]
    float* out = (float*)d_out;

    k_init<<<32, 256, 0, stream>>>((unsigned*)d_ws);

    dim3 g1(AN / ANCH_PER_BLK, BN);   // (64, 32) -> 32 waves/CU
    k_fused<<<g1, TPB, 0, stream>>>(anchors, gt, WS_GKEY(d_ws), WS_ABYTE(d_ws));

    dim3 g2(NBLK, BN);                // 256 blocks: distributed streaming
    k_prep<<<g2, 1024, 0, stream>>>(bbox, conf, gt, WS_GKEY(d_ws), WS_ABYTE(d_ws),
                                    WS_HIST1(d_ws), WS_NUMPOS(d_ws),
                                    WS_TOTL(d_ws), WS_TOTPC(d_ws));

    k_neg<<<BN, 1024, 0, stream>>>(conf, WS_ABYTE(d_ws), WS_GKEY(d_ws), WS_HIST1(d_ws),
                                   WS_NUMPOS(d_ws), WS_TOTN(d_ws), WS_TOTL(d_ws),
                                   WS_TOTPC(d_ws), WS_DONE(d_ws), out);
}

// Round 10
// 76.274 us; speedup vs baseline: 1.5818x; 1.0097x over previous
//
#include <hip/hip_runtime.h>
#include <cmath>

#define BN 32
#define AN 32768
#define GN 64
#define TPB 256                    // k_fused threads per block
#define ANCH_PER_BLK 512           // 2 anchors per thread
#define NBLK 8                     // k_prep blocks per image
#define CAP 8192                   // LDS survivor capacity in k_neg

// ---------------- workspace layout (bytes) ----------------
// 0       : int   totN         (atomic)
// 4       : float totL         (atomic)
// 8       : float totPC        (atomic)
// 12      : uint  done         (finished-image counter)
// 16      : int   num_pos[32]  (per-image, bit7-positives only)
// 1024    : u64   gkey2[B][64][64]  (1 MB, plain stores: [b][block][g])
// 1049600 : u32   hist1[B][4096]    (512 KB, global atomicAdd; zeroed by k_fused)
// 1573888 : u8    abyte[B*A]        (1 MB, fully overwritten)
#define WS_TOTN(ws)   ((int*)(ws))
#define WS_TOTL(ws)   ((float*)((char*)(ws) + 4))
#define WS_TOTPC(ws)  ((float*)((char*)(ws) + 8))
#define WS_DONE(ws)   ((unsigned*)((char*)(ws) + 12))
#define WS_NUMPOS(ws) ((int*)((char*)(ws) + 16))
#define WS_GKEY2(ws)  ((unsigned long long*)((char*)(ws) + 1024))
#define WS_HIST1(ws)  ((unsigned*)((char*)(ws) + 1049600))
#define WS_ABYTE(ws)  ((unsigned char*)((char*)(ws) + 1573888))

#define LN2F 0.69314718056f

__device__ __forceinline__ float negloss(float p) {
    // -log(1-p); p <= 1-1e-4 -> clamp never binds (kept for safety).
    // MUST be identical everywhere (bit-identical histogram bins).
    return -fmaxf(__log2f(1.0f - p) * LN2F, -100.0f);
}
__device__ __forceinline__ float posbce(float p) {
    return -fmaxf(__log2f(p) * LN2F, -100.0f);
}
__device__ __forceinline__ float smoothl1(float4 bb, float4 m) {
    float d0 = (bb.x + bb.z) * 0.5f - m.x;
    float d1 = (bb.y + bb.w) * 0.5f - m.y;
    float d2 = (bb.z - bb.x) - m.z;
    float d3 = (bb.w - bb.y) - m.w;
    float ad = fabsf(d0); float s = (ad < 1.0f) ? 0.5f * d0 * d0 : ad - 0.5f;
    ad = fabsf(d1); s += (ad < 1.0f) ? 0.5f * d1 * d1 : ad - 0.5f;
    ad = fabsf(d2); s += (ad < 1.0f) ? 0.5f * d2 * d2 : ad - 0.5f;
    ad = fabsf(d3); s += (ad < 1.0f) ? 0.5f * d3 * d3 : ad - 0.5f;
    return s;
}

// ===================== k_fused =====================
// Every (anchor, gt) IoU exactly once. Duplicated LDS GT table (no index wrap;
// unrolled imm-offset reads). Per-anchor best-g thread-local; per-gt best via
// LDS ds_max_u64 on duplicated targets, merged + plain-stored to gkey2 slice.
// Also: distributed zeroing of hist1 + scalars (replaces k_init).
__global__ __launch_bounds__(TPB, 8) void k_fused(const float* __restrict__ anchors,
                                                  const float* __restrict__ gt,
                                                  unsigned long long* __restrict__ gkey2,
                                                  unsigned char* __restrict__ abyte,
                                                  unsigned* __restrict__ hist1,
                                                  unsigned* __restrict__ scal) {
    __shared__ float sgt0[128], sgt1[128], sgt2[128], sgt3[128], sgt4[128];
    __shared__ unsigned long long skey2[128];

    int b = blockIdx.y;
    int tid = threadIdx.x;
    int lane = tid & 63;
    int blockbase = blockIdx.x * ANCH_PER_BLK;
    int blid = b * 64 + blockIdx.x;              // 0..2047

    // distributed init (consumed only by later kernels; stream-ordered)
    if (tid < 64) hist1[blid * 64 + tid] = 0u;
    if (blid == 0 && tid < 36) scal[tid] = 0u;   // totN/totL/totPC/done + num_pos[32]

    if (tid < GN) {
        float4 g = ((const float4*)gt)[b * GN + tid];
        float area = (g.z - g.x) * (g.w - g.y);
        sgt0[tid] = g.x; sgt0[tid + 64] = g.x;
        sgt1[tid] = g.y; sgt1[tid + 64] = g.y;
        sgt2[tid] = g.z; sgt2[tid + 64] = g.z;
        sgt3[tid] = g.w; sgt3[tid + 64] = g.w;
        sgt4[tid] = area; sgt4[tid + 64] = area;
    }
    if (tid < 128) skey2[tid] = 0ull;
    __syncthreads();

    unsigned a0 = (unsigned)(blockbase + tid);
    unsigned a1 = a0 + TPB;
    float4 ab0 = ((const float4*)anchors)[a0];
    float4 ab1 = ((const float4*)anchors)[a1];
    float sa0 = (ab0.z - ab0.x) * (ab0.w - ab0.y) + 1e-6f;
    float sa1 = (ab1.z - ab1.x) * (ab1.w - ab1.y) + 1e-6f;
    unsigned na0 = ~a0, na1 = ~a1;

    float bv0 = -1.0f, bv1 = -1.0f;
    int bi0 = 0, bi1 = 0;                        // rotated idx of best g

#pragma unroll 8
    for (int j = 0; j < GN; ++j) {
        int idx = lane + j;                      // 0..126, no wrap (duplicated LDS)
        float gx0 = sgt0[idx], gy0 = sgt1[idx];
        float gx1 = sgt2[idx], gy1 = sgt3[idx];
        float gA  = sgt4[idx];

        float d0 = sa0 + gA, d1 = sa1 + gA;

        float iw0 = fminf(ab0.z, gx1) - fmaxf(ab0.x, gx0);
        float ih0 = fminf(ab0.w, gy1) - fmaxf(ab0.y, gy0);
        float in0 = fmaxf(iw0, 0.0f) * fmaxf(ih0, 0.0f);
        float v0 = in0 * __builtin_amdgcn_rcpf(d0 - in0);

        float iw1 = fminf(ab1.z, gx1) - fmaxf(ab1.x, gx0);
        float ih1 = fminf(ab1.w, gy1) - fmaxf(ab1.y, gy0);
        float in1 = fmaxf(iw1, 0.0f) * fmaxf(ih1, 0.0f);
        float v1 = in1 * __builtin_amdgcn_rcpf(d1 - in1);

        if (v0 > bv0) { bv0 = v0; bi0 = idx; }   // strict >: first in rotated order
        if (v1 > bv1) { bv1 = v1; bi1 = idx; }

        // per-gt 2->1 (a0 < a1; strict > keeps min anchor idx on exact ties)
        float vm = v0; unsigned nam = na0;
        if (v1 > vm) { vm = v1; nam = na1; }
        unsigned long long key = ((unsigned long long)__float_as_uint(vm) << 32)
                               | (unsigned long long)nam;
        atomicMax(&skey2[idx], key);             // ds_max_u64, distinct addr per lane
    }
    __syncthreads();

    size_t base = (size_t)b * AN;
    abyte[base + a0] = (unsigned char)(((bv0 > 0.5f) ? 0x80u : 0u) | ((unsigned)bi0 & 63u));
    abyte[base + a1] = (unsigned char)(((bv1 > 0.5f) ? 0x80u : 0u) | ((unsigned)bi1 & 63u));

    if (tid < GN) {
        unsigned long long k2 = skey2[tid];
        unsigned long long k3 = skey2[tid + 64];
        gkey2[(size_t)blid * 64 + tid] = (k2 > k3) ? k2 : k3;   // coalesced slice
    }
}

// ===================== k_prep =====================
// grid (NBLK, 32), 1024 thr; 4096 anchors/block. bit7-positives only (forced
// corrections applied exactly in k_neg). LDS hist -> global atomicAdd.
__global__ __launch_bounds__(1024) void k_prep(const float* __restrict__ bbox,
                                               const float* __restrict__ conf,
                                               const float* __restrict__ gt,
                                               const unsigned char* __restrict__ abyte,
                                               unsigned* __restrict__ hist1,
                                               int* __restrict__ num_pos,
                                               float* __restrict__ totL,
                                               float* __restrict__ totPC) {
    __shared__ unsigned hist[4096];
    __shared__ float4 sgcs[GN];
    __shared__ float redL[16], redP[16];
    __shared__ int   redN[16];

    int blk = blockIdx.x, b = blockIdx.y, tid = threadIdx.x;
    int abase = blk * 4096;

    for (int i = tid; i < 4096; i += 1024) hist[i] = 0;
    if (tid < GN) {
        float4 g = ((const float4*)gt)[b * GN + tid];
        sgcs[tid] = make_float4((g.x + g.z) * 0.5f, (g.y + g.w) * 0.5f,
                                g.z - g.x, g.w - g.y);
    }
    __syncthreads();

    int li = tid * 4;
    size_t ia = (size_t)b * AN + abase + li;
    float4 c4 = ((const float4*)conf)[ia >> 2];
    uchar4 by4 = ((const uchar4*)abyte)[ia >> 2];
    float cc[4] = {c4.x, c4.y, c4.z, c4.w};
    unsigned bys[4] = {by4.x, by4.y, by4.z, by4.w};

    float locv = 0.0f, pcv = 0.0f;
    int npv = 0;
#pragma unroll
    for (int e = 0; e < 4; ++e) {
        float p = cc[e];
        if (bys[e] & 0x80u) {
            float4 bb = ((const float4*)bbox)[ia + e];
            locv += smoothl1(bb, sgcs[bys[e] & 63u]);
            pcv += posbce(p);
            npv += 1;
            // no hist add: bin 0 is never selected/summed
        } else {
            float v = negloss(p);
            atomicAdd(&hist[__float_as_uint(v) >> 20], 1u);
        }
    }

    for (int off = 32; off; off >>= 1) {
        locv += __shfl_xor(locv, off);
        pcv  += __shfl_xor(pcv, off);
        npv  += __shfl_xor(npv, off);
    }
    int wave = tid >> 6, lane = tid & 63;
    if (lane == 0) { redL[wave] = locv; redP[wave] = pcv; redN[wave] = npv; }
    __syncthreads();
    if (tid == 0) {
        float L = 0.0f, P = 0.0f; int N = 0;
        for (int w = 0; w < 16; ++w) { L += redL[w]; P += redP[w]; N += redN[w]; }
        if (N) atomicAdd(&num_pos[b], N);
        atomicAdd(totL, L);
        atomicAdd(totPC, P);
    }
    __syncthreads();
    for (int i = tid; i < 4096; i += 1024) {
        unsigned c = hist[i];
        if (c) atomicAdd(&hist1[b * 4096 + i], c);
    }
}

// ===================== k_neg =====================
// One block per image. gkey2 64-slice max-reduce -> forced bitmap + exact
// corrections (hist--, np/loc/posBCE). Then: round-1 select, ONE streaming
// pass (strictly-above sum + LDS compaction), two tiny radix rounds,
// device-scope finalize (last image writes out[]).
__global__ __launch_bounds__(1024) void k_neg(const float* __restrict__ bbox,
                                              const float* __restrict__ conf,
                                              const float* __restrict__ gt,
                                              const unsigned char* __restrict__ abyte,
                                              const unsigned long long* __restrict__ gkey2,
                                              const unsigned* __restrict__ hist1,
                                              const int* __restrict__ num_pos,
                                              int* __restrict__ totN,
                                              float* __restrict__ totL,
                                              float* __restrict__ totPC,
                                              unsigned* __restrict__ done,
                                              float* __restrict__ out) {
    __shared__ unsigned hist[4096];
    __shared__ float sv[CAP];
    __shared__ unsigned bitmap[1024];
    __shared__ float4 sgcs[GN];
    __shared__ unsigned sforced[GN];
    __shared__ float redL[16];
    __shared__ int   s_fn; __shared__ float s_fl, s_fp;
    __shared__ unsigned s_cnt, s_sel, s_krem;

    int b = blockIdx.x, tid = threadIdx.x;
    int lane = tid & 63, wave = tid >> 6;

    for (int i = tid; i < 4096; i += 1024) hist[i] = hist1[b * 4096 + i];
    bitmap[tid] = 0;
    if (tid == 0) s_cnt = 0;
    if (tid < GN) {
        float4 g = ((const float4*)gt)[b * GN + tid];
        sgcs[tid] = make_float4((g.x + g.z) * 0.5f, (g.y + g.w) * 0.5f,
                                g.z - g.x, g.w - g.y);
    }
    __syncthreads();

    // ---- per-gt best anchor: exact max over the 64 block slices (coalesced)
    if (tid < GN) {
        unsigned long long m = gkey2[(size_t)(b * 64) * 64 + tid];
#pragma unroll 8
        for (int t = 1; t < 64; ++t) {
            unsigned long long v = gkey2[(size_t)(b * 64 + t) * 64 + tid];
            if (v > m) m = v;
        }
        unsigned idx = ~(unsigned)(m & 0xFFFFFFFFull);
        sforced[tid] = idx;
        atomicOr(&bitmap[idx >> 5], 1u << (idx & 31));
    }
    __syncthreads();

    // ---- forced corrections (wave 0): dedupe, fix hist + scalars exactly
    if (tid < GN) {
        unsigned a = sforced[tid];
        bool own = true;
        for (int t = 0; t < tid; ++t) if (sforced[t] == a) { own = false; break; }
        int fn = 0; float fl = 0.0f, fp = 0.0f;
        if (own) {
            unsigned by = abyte[(size_t)b * AN + a];
            if (!(by & 0x80u)) {                 // forced-only positive
                float p = conf[(size_t)b * AN + a];
                float v = negloss(p);
                atomicAdd(&hist[__float_as_uint(v) >> 20], 0xFFFFFFFFu);  // -1
                fn = 1;
                fp = posbce(p);
                float4 bb = ((const float4*)bbox)[(size_t)b * AN + a];
                fl = smoothl1(bb, sgcs[by & 63u]);
            }
        }
        for (int off = 32; off; off >>= 1) {
            fn += __shfl_xor(fn, off);
            fl += __shfl_xor(fl, off);
            fp += __shfl_xor(fp, off);
        }
        if (tid == 0) { s_fn = fn; s_fl = fl; s_fp = fp; }
    }
    __syncthreads();

    int np = num_pos[b] + s_fn;
    unsigned k = (unsigned)min(3 * np, AN - np);
    float nc = 0.0f;

    if (k > 0) {
        // ---- round-1 select over hist[4096] (descending): two-level wave scan
        if (tid < 64) {
            unsigned c = 0;
            int base = tid * 64;
#pragma unroll
            for (int i = 0; i < 64; ++i) c += hist[base + ((tid + i) & 63)];  // rotated
            unsigned S = c;
#pragma unroll
            for (int d = 1; d < 64; d <<= 1) { unsigned t = __shfl_down(S, d); if (tid + d < 64) S += t; }
            unsigned E = S - c;
            unsigned long long mk = __ballot(E < k && k <= S);
            int bl = __ffsll(mk) - 1;
            unsigned kin = k - __shfl(E, bl);
            unsigned h = hist[bl * 64 + tid];
            unsigned S2 = h;
#pragma unroll
            for (int d = 1; d < 64; d <<= 1) { unsigned t = __shfl_down(S2, d); if (tid + d < 64) S2 += t; }
            unsigned E2 = S2 - h;
            unsigned long long mk2 = __ballot(E2 < kin && kin <= S2);
            int bin_l = __ffsll(mk2) - 1;
            unsigned E2b = __shfl(E2, bin_l);
            if (tid == 0) { s_sel = (unsigned)(bl * 64 + bin_l); s_krem = kin - E2b; }
        }
        __syncthreads();
        unsigned sel1 = s_sel, krem1 = s_krem;
        __syncthreads();
        for (int i = tid; i < 4096; i += 1024) hist[i] = 0;
        __syncthreads();

        // ---- ONE streaming pass: strictly-above sum + LDS compaction
        float acc = 0.0f;
        const float4* c4p = (const float4*)(conf + (size_t)b * AN);
        const uchar4* b4p = (const uchar4*)(abyte + (size_t)b * AN);
#pragma unroll
        for (int it = 0; it < 8; ++it) {
            int i4 = tid + it * 1024;
            float4 c4 = c4p[i4];
            uchar4 u4 = b4p[i4];
            int li = i4 * 4;
            unsigned fb = (bitmap[li >> 5] >> (li & 31)) & 0xFu;
            float cc[4] = {c4.x, c4.y, c4.z, c4.w};
            unsigned by[4] = {u4.x, u4.y, u4.z, u4.w};
#pragma unroll
            for (int e = 0; e < 4; ++e) {
                bool pos = (by[e] & 0x80u) || ((fb >> e) & 1u);
                float v = pos ? 0.0f : negloss(cc[e]);
                unsigned bin = __float_as_uint(v) >> 20;
                if (bin > sel1) acc += v;
                else if (bin == sel1) {
                    unsigned p = atomicAdd(&s_cnt, 1u);
                    if (p < CAP) sv[p] = v;
                }
            }
        }
        __syncthreads();
        unsigned n = min(s_cnt, (unsigned)CAP);

        // ---- round A: 12 bits (key>>8)&0xFFF over survivors
        for (unsigned i = tid; i < n; i += 1024)
            atomicAdd(&hist[(__float_as_uint(sv[i]) >> 8) & 0xFFFu], 1u);
        __syncthreads();
        if (tid < 64) {
            unsigned c = 0;
            int base = tid * 64;
#pragma unroll
            for (int i = 0; i < 64; ++i) c += hist[base + ((tid + i) & 63)];
            unsigned S = c;
#pragma unroll
            for (int d = 1; d < 64; d <<= 1) { unsigned t = __shfl_down(S, d); if (tid + d < 64) S += t; }
            unsigned E = S - c;
            unsigned long long mk = __ballot(E < krem1 && krem1 <= S);
            int bl = __ffsll(mk) - 1;
            unsigned kin = krem1 - __shfl(E, bl);
            unsigned h = hist[bl * 64 + tid];
            unsigned S2 = h;
#pragma unroll
            for (int d = 1; d < 64; d <<= 1) { unsigned t = __shfl_down(S2, d); if (tid + d < 64) S2 += t; }
            unsigned E2 = S2 - h;
            unsigned long long mk2 = __ballot(E2 < kin && kin <= S2);
            int bin_l = __ffsll(mk2) - 1;
            unsigned E2b = __shfl(E2, bin_l);
            if (tid == 0) { s_sel = (unsigned)(bl * 64 + bin_l); s_krem = kin - E2b; }
        }
        __syncthreads();
        unsigned selA = s_sel, krem2 = s_krem;
        __syncthreads();
        if (tid < 256) hist[tid] = 0;
        __syncthreads();

        // ---- round B: low 8 bits, masked to selA
        for (unsigned i = tid; i < n; i += 1024) {
            unsigned key = __float_as_uint(sv[i]);
            if (((key >> 8) & 0xFFFu) == selA) atomicAdd(&hist[key & 0xFFu], 1u);
        }
        __syncthreads();
        if (tid < 64) {
            int base = tid * 4;
            unsigned c = 0;
#pragma unroll
            for (int i = 0; i < 4; ++i) c += hist[base + i];
            unsigned S = c;
#pragma unroll
            for (int d = 1; d < 64; d <<= 1) { unsigned t = __shfl_down(S, d); if (tid + d < 64) S += t; }
            unsigned E = S - c;
            unsigned long long mk = __ballot(E < krem2 && krem2 <= S);
            int bl = __ffsll(mk) - 1;
            if (tid == bl) {
                unsigned cum = E;
                for (int bin = base + 3; bin >= base; --bin) {
                    unsigned h = hist[bin];
                    cum += h;
                    if (cum >= krem2) { s_sel = (unsigned)bin; s_krem = krem2 - (cum - h); break; }
                }
            }
        }
        __syncthreads();
        unsigned Tkey = (sel1 << 20) | (selA << 8) | s_sel;
        unsigned kremF = s_krem;
        float T = __uint_as_float(Tkey);   // exact k-th largest value

        float part = acc;
        for (unsigned i = tid; i < n; i += 1024)
            if (__float_as_uint(sv[i]) > Tkey) part += sv[i];
        for (int off = 32; off; off >>= 1) part += __shfl_xor(part, off);
        if (lane == 0) redL[wave] = part;
        __syncthreads();
        if (tid == 0) {
            float t = 0.0f;
            for (int w = 0; w < 16; ++w) t += redL[w];
            nc = t + (float)kremF * T;
        }
    }

    // ---- finalize: cross-block traffic via device-scope atomics only
    if (tid == 0) {
        atomicAdd(totN, np);
        atomicAdd(totL, s_fl);
        atomicAdd(totPC, s_fp + nc);
        __threadfence();
        unsigned old = atomicAdd(done, 1u);
        if (old == BN - 1) {
            int   N  = atomicAdd(totN, 0);
            float L  = atomicAdd(totL, 0.0f);
            float PC = atomicAdd(totPC, 0.0f);
            float tp = (float)max(1, N);
            float loc_loss = L / tp;
            float conf_loss = PC / tp;
            out[0] = loc_loss + conf_loss;
            out[1] = conf_loss;
            out[2] = loc_loss;
        }
    }
}

extern "C" void kernel_launch(void* const* d_in, const int* in_sizes, int n_in,
                              void* d_out, int out_size, void* d_ws, size_t ws_size,
                              hipStream_t stream) {
    const float* bbox    = (const float*)d_in[0];   // [B,A,4]
    const float* conf    = (const float*)d_in[1];   // [B,A]
    const float* anchors = (const float*)d_in[2];   // [A,4]
    const float* gt      = (const float*)d_in[3];   // [B,G,4]
    float* out = (float*)d_out;

    dim3 g1(AN / ANCH_PER_BLK, BN);   // (64, 32) -> 32 waves/CU
    k_fused<<<g1, TPB, 0, stream>>>(anchors, gt, WS_GKEY2(d_ws), WS_ABYTE(d_ws),
                                    WS_HIST1(d_ws), (unsigned*)d_ws);

    dim3 g2(NBLK, BN);                // 256 blocks: distributed streaming
    k_prep<<<g2, 1024, 0, stream>>>(bbox, conf, gt, WS_ABYTE(d_ws),
                                    WS_HIST1(d_ws), WS_NUMPOS(d_ws),
                                    WS_TOTL(d_ws), WS_TOTPC(d_ws));

    k_neg<<<BN, 1024, 0, stream>>>(bbox, conf, gt, WS_ABYTE(d_ws), WS_GKEY2(d_ws),
                                   WS_HIST1(d_ws), WS_NUMPOS(d_ws),
                                   WS_TOTN(d_ws), WS_TOTL(d_ws), WS_TOTPC(d_ws),
                                   WS_DONE(d_ws), out);
}